// Round 9
// baseline (894.507 us; speedup 1.0000x reference)
//
#include <hip/hip_runtime.h>
#include <hip/hip_fp16.h>

#define NNODES 100000
#define NEDGES 1600000
#define DIM 128
#define NB ((NNODES + 63) / 64)          // 1563 buckets of 64 nodes
#define NCH 128                          // scatter blocks / edge chunks
#define CHUNK ((NEDGES + NCH - 1) / NCH) // 12500 edges per chunk
#define EBUF 2560                        // per-bucket LDS edge capacity
#define LSTR 136                         // padded LDS stride (halfs)
#define NSL16 ((size_t)NNODES * 16)      // slice-major slice stride (halfs)

typedef _Float16 f16x8 __attribute__((ext_vector_type(8)));
typedef float f32x4 __attribute__((ext_vector_type(4)));

__device__ __forceinline__ float leaky02(float t) { return t > 0.f ? t : 0.2f * t; }

union H8u { uint2 u; __half2 h[2]; };

// slice-major fp16 feature layout: elem(node, col) = buf[(col>>4)*NSL16 + node*16 + (col&15)]

// ============ MFMA fp16 GEMM + fused attention dots ==================
// block: 64 rows x 128 cols, 4 waves; wave: 16 rows x 128 cols.
// C: acc[ct][j] = H[row=(lane>>4)*4+j][col=ct*16+(lane&15)]  (m89-verified)
template <bool XF16>
__global__ __launch_bounds__(256) void gemm_mfma(const float* __restrict__ X,
                                                 const __half* __restrict__ X16,
                                                 const float* __restrict__ W,
                                                 const float* __restrict__ as_,
                                                 const float* __restrict__ ad_,
                                                 __half* __restrict__ H,
                                                 float* __restrict__ s,
                                                 float* __restrict__ d, int n) {
    __shared__ __half As[64][LSTR];
    __shared__ __half Wt[128][LSTR];
    int t = threadIdx.x;
    int brow = blockIdx.x * 64;

    if (XF16) {
        // X16 is slice-major
        for (int i = t; i < 64 * 16; i += 256) {
            int r = i >> 4, c8 = (i & 15) * 8;
            int gr = brow + r;
            int sl = c8 >> 4, off = c8 & 15;
            uint4 v = (gr < n) ? *(const uint4*)(X16 + (size_t)sl * NSL16 + (size_t)gr * 16 + off)
                               : make_uint4(0u, 0u, 0u, 0u);
            *(uint4*)&As[r][c8] = v;
        }
    } else {
        for (int i = t; i < 64 * 32; i += 256) {
            int r = i >> 5, c4 = (i & 31) * 4;
            int gr = brow + r;
            float4 v = (gr < n) ? *(const float4*)(X + (size_t)gr * 128 + c4)
                                : make_float4(0.f, 0.f, 0.f, 0.f);
            As[r][c4 + 0] = __float2half_rn(v.x);
            As[r][c4 + 1] = __float2half_rn(v.y);
            As[r][c4 + 2] = __float2half_rn(v.z);
            As[r][c4 + 3] = __float2half_rn(v.w);
        }
    }
    for (int i = t; i < 128 * 32; i += 256) {
        int k = i >> 5, n4 = (i & 31) * 4;
        float4 wv = *(const float4*)(W + k * 128 + n4);
        Wt[n4 + 0][k] = __float2half_rn(wv.x);
        Wt[n4 + 1][k] = __float2half_rn(wv.y);
        Wt[n4 + 2][k] = __float2half_rn(wv.z);
        Wt[n4 + 3][k] = __float2half_rn(wv.w);
    }
    __syncthreads();

    int wid  = t >> 6;
    int lane = t & 63;
    int lrow = lane & 15;
    int lkg  = lane >> 4;
    int r0   = wid * 16;

    f32x4 acc[8] = {};
#pragma unroll
    for (int kk = 0; kk < 128; kk += 32) {
        f16x8 af = *(const f16x8*)&As[r0 + lrow][kk + lkg * 8];
#pragma unroll
        for (int ct = 0; ct < 8; ++ct) {
            f16x8 bf = *(const f16x8*)&Wt[ct * 16 + lrow][kk + lkg * 8];
            acc[ct] = __builtin_amdgcn_mfma_f32_16x16x32_f16(af, bf, acc[ct], 0, 0, 0);
        }
    }

    float sp[4] = {0.f, 0.f, 0.f, 0.f};
    float dp[4] = {0.f, 0.f, 0.f, 0.f};
#pragma unroll
    for (int ct = 0; ct < 8; ++ct) {
        float a_s = as_[ct * 16 + lrow];
        float a_d = ad_[ct * 16 + lrow];
#pragma unroll
        for (int j = 0; j < 4; ++j) {
            sp[j] += acc[ct][j] * a_s;
            dp[j] += acc[ct][j] * a_d;
        }
    }
#pragma unroll
    for (int j = 0; j < 4; ++j) {
        int gr = brow + r0 + lkg * 4 + j;
        if (gr < n) {
#pragma unroll
            for (int ct = 0; ct < 8; ++ct)   // slice-major store: slice == ct
                H[(size_t)ct * NSL16 + (size_t)gr * 16 + lrow] = __float2half_rn(acc[ct][j]);
        }
    }
#pragma unroll
    for (int off = 1; off < 16; off <<= 1)
#pragma unroll
        for (int j = 0; j < 4; ++j) {
            sp[j] += __shfl_xor(sp[j], off);
            dp[j] += __shfl_xor(dp[j], off);
        }
    if (lrow == 0)
#pragma unroll
        for (int j = 0; j < 4; ++j) {
            int gr = brow + r0 + lkg * 4 + j;
            if (gr < n) { s[gr] = sp[j]; d[gr] = dp[j]; }
        }
}

// ============ bucket-sort CSR build (no global atomics) =============
__global__ __launch_bounds__(512) void bucket_count(const int* __restrict__ dst,
                                                    int* __restrict__ blockcounts) {
    __shared__ int hist[NB];
    int b = blockIdx.x, t = threadIdx.x;
    for (int i = t; i < NB; i += 512) hist[i] = 0;
    __syncthreads();
    int e0 = b * CHUNK, e1 = min(NEDGES, e0 + CHUNK);
    for (int e = e0 + t; e < e1; e += 512)
        atomicAdd(&hist[dst[e] >> 6], 1);
    __syncthreads();
    for (int i = t; i < NB; i += 512)
        blockcounts[i * NCH + b] = hist[i];
}

__global__ __launch_bounds__(NCH) void bucket_scan_a(int* __restrict__ blockcounts,
                                                     int* __restrict__ btotal) {
    int bin = blockIdx.x, t = threadIdx.x;
    int v = blockcounts[bin * NCH + t];
    int incl = v;
#pragma unroll
    for (int off = 1; off < 64; off <<= 1) {
        int u = __shfl_up(incl, off, 64);
        if ((t & 63) >= off) incl += u;
    }
    __shared__ int wsum;
    if (t == 63) wsum = incl;
    __syncthreads();
    int excl = incl - v + ((t >= 64) ? wsum : 0);
    blockcounts[bin * NCH + t] = excl;
    if (t == NCH - 1) btotal[bin] = excl + v;
}

__global__ __launch_bounds__(1024) void bucket_scan_b(const int* __restrict__ btotal,
                                                      int* __restrict__ bbase) {
    __shared__ int ts[2][1024];
    int t = threadIdx.x;
    int b0 = t * 2;
    int c0 = (b0 < NB)     ? btotal[b0]     : 0;
    int c1 = (b0 + 1 < NB) ? btotal[b0 + 1] : 0;
    int sum = c0 + c1;
    ts[0][t] = sum;
    __syncthreads();
    int sb = 0;
    for (int off = 1; off < 1024; off <<= 1) {
        int v = ts[sb][t] + ((t >= off) ? ts[sb][t - off] : 0);
        ts[sb ^ 1][t] = v;
        sb ^= 1;
        __syncthreads();
    }
    int excl = ts[sb][t] - sum;
    if (b0 < NB)     bbase[b0]     = excl;
    if (b0 + 1 < NB) bbase[b0 + 1] = excl + c0;
    if (t == 1023) bbase[NB] = ts[sb][1023];
}

__global__ __launch_bounds__(512) void bucket_scatter(const int* __restrict__ src,
                                                      const int* __restrict__ dst,
                                                      const int* __restrict__ blockcounts,
                                                      const int* __restrict__ bbase,
                                                      int* __restrict__ packed) {
    __shared__ int cur[NB];
    int b = blockIdx.x, t = threadIdx.x;
    for (int i = t; i < NB; i += 512) cur[i] = bbase[i] + blockcounts[i * NCH + b];
    __syncthreads();
    int e0 = b * CHUNK, e1 = min(NEDGES, e0 + CHUNK);
    for (int e = e0 + t; e < e1; e += 512) {
        int dv = dst[e];
        int bin = dv >> 6;
        int p = atomicAdd(&cur[bin], 1);
        packed[p] = ((dv & 63) << 17) | src[e];
    }
}

__global__ __launch_bounds__(256) void bucket_csr(const int* __restrict__ packed,
                                                  const int* __restrict__ bbase,
                                                  int* __restrict__ rowptr,
                                                  int* __restrict__ csr_src) {
    __shared__ int ebuf[EBUF];
    __shared__ int hist[64], cur[64];
    int i = blockIdx.x, t = threadIdx.x;
    int base = bbase[i], cnt = bbase[i + 1] - base;
    bool inl = (cnt <= EBUF);
    if (inl) for (int j = t; j < cnt; j += 256) ebuf[j] = packed[base + j];
    if (t < 64) hist[t] = 0;
    __syncthreads();
    for (int j = t; j < cnt; j += 256) {
        int v = inl ? ebuf[j] : packed[base + j];
        atomicAdd(&hist[v >> 17], 1);
    }
    __syncthreads();
    if (t < 64) {
        int h = hist[t];
        int incl = h;
#pragma unroll
        for (int off = 1; off < 64; off <<= 1) {
            int u = __shfl_up(incl, off, 64);
            if (t >= off) incl += u;
        }
        int ex = incl - h;
        cur[t] = ex;
        int node = i * 64 + t;
        if (node <= NNODES) rowptr[node] = base + ex;
    }
    __syncthreads();
    for (int j = t; j < cnt; j += 256) {
        int v = inl ? ebuf[j] : packed[base + j];
        int off = atomicAdd(&cur[v >> 17], 1);
        csr_src[base + off] = v & 0x1FFFF;
    }
}

// ============ per-edge normalized attention weights, packed u32 =======
// packed2[e] = (src << 15) | round(alpha * 32767);  selfpk[n] likewise.
__global__ __launch_bounds__(256) void gat_alpha(const int* __restrict__ rowptr,
                                                 const int* __restrict__ csr,
                                                 const float* __restrict__ s,
                                                 const float* __restrict__ d,
                                                 unsigned* __restrict__ packed2,
                                                 unsigned* __restrict__ selfpk, int n) {
    int node = blockIdx.x * 4 + (threadIdx.x >> 6);
    if (node >= n) return;
    int lane = threadIdx.x & 63;
    int base = rowptr[node];
    int deg  = rowptr[node + 1] - base;
    float dnode = d[node], snode = s[node];

    if (deg < 64) {
        int cnt = deg + 1;
        int si  = (lane < deg) ? csr[base + lane] : node;
        float sv = (lane < deg) ? s[si] : snode;
        float lv = leaky02(sv + dnode);
        float lm = (lane < cnt) ? lv : -1e30f;
#pragma unroll
        for (int off = 32; off; off >>= 1) lm = fmaxf(lm, __shfl_xor(lm, off));
        float w = (lane < cnt) ? expf(lv - lm) : 0.f;
        float denom = w;
#pragma unroll
        for (int off = 32; off; off >>= 1) denom += __shfl_xor(denom, off);
        unsigned q = (unsigned)__float2int_rn(w / denom * 32767.f);
        unsigned pk = ((unsigned)si << 15) | q;
        if (lane < deg)        packed2[base + lane] = pk;
        else if (lane == deg)  selfpk[node] = pk;
    } else {
        float m = -1e30f;
        for (int c = 0; c <= deg; c += 64) {
            int idx = c + lane;
            float lv = -1e30f;
            if (idx < deg)       lv = leaky02(s[csr[base + idx]] + dnode);
            else if (idx == deg) lv = leaky02(snode + dnode);
            m = fmaxf(m, lv);
        }
#pragma unroll
        for (int off = 32; off; off >>= 1) m = fmaxf(m, __shfl_xor(m, off));
        float denom = 0.f;
        for (int c = 0; c <= deg; c += 64) {
            int idx = c + lane;
            if (idx < deg)       denom += expf(leaky02(s[csr[base + idx]] + dnode) - m);
            else if (idx == deg) denom += expf(leaky02(snode + dnode) - m);
        }
#pragma unroll
        for (int off = 32; off; off >>= 1) denom += __shfl_xor(denom, off);
        for (int c = 0; c <= deg; c += 64) {
            int idx = c + lane;
            if (idx < deg) {
                int si = csr[base + idx];
                float w = expf(leaky02(s[si] + dnode) - m);
                packed2[base + idx] = ((unsigned)si << 15) |
                                      (unsigned)__float2int_rn(w / denom * 32767.f);
            } else if (idx == deg) {
                float w = expf(leaky02(snode + dnode) - m);
                selfpk[node] = ((unsigned)node << 15) |
                               (unsigned)__float2int_rn(w / denom * 32767.f);
            }
        }
    }
}

// ============ sliced aggregation: A[:, slice] = sum alpha * H[src, slice]
// slice = blockIdx % 8 -> XCD-local 3.2MB H-slice (L2-resident).
// wave: 16 edge-slots x 4 col-lanes (uint2 = 32B row-slice); 8 nodes/wave.
__global__ __launch_bounds__(256) void gat_agg(const int* __restrict__ rowptr,
                                               const unsigned* __restrict__ packed2,
                                               const unsigned* __restrict__ selfpk,
                                               const __half* __restrict__ H,
                                               const float* __restrict__ bias,
                                               __half* __restrict__ A16, int n) {
    int sl  = blockIdx.x & 7;
    int ng  = blockIdx.x >> 3;
    int wid = threadIdx.x >> 6;
    int lane = threadIdx.x & 63;
    int es = lane >> 2;          // edge slot 0..15
    int cp = lane & 3;           // col quad 0..3
    const __half* Hs = H + (size_t)sl * NSL16;
    __half* As = A16 + (size_t)sl * NSL16;
    float b0 = bias[sl * 16 + cp * 4 + 0];
    float b1 = bias[sl * 16 + cp * 4 + 1];
    float b2 = bias[sl * 16 + cp * 4 + 2];
    float b3 = bias[sl * 16 + cp * 4 + 3];

    int node0 = (ng * 4 + wid) * 8;
    int nend  = min(node0 + 8, n);
    for (int node = node0; node < nend; ++node) {
        int base = rowptr[node];
        int deg  = rowptr[node + 1] - base;
        f32x4 acc = {0.f, 0.f, 0.f, 0.f};
        for (int c = 0; c <= deg; c += 16) {
            int e = c + es;
            unsigned pk = 0u;
            if (e < deg)        pk = __builtin_nontemporal_load(&packed2[base + e]);
            else if (e == deg)  pk = selfpk[node];
            float a = (float)(pk & 0x7fffu) * (1.f / 32767.f);
            unsigned srcv = pk >> 15;
            H8u hv;
            hv.u = *(const uint2*)(Hs + (size_t)srcv * 16 + cp * 4);
            float2 a01 = __half22float2(hv.h[0]);
            float2 a23 = __half22float2(hv.h[1]);
            acc[0] += a * a01.x;
            acc[1] += a * a01.y;
            acc[2] += a * a23.x;
            acc[3] += a * a23.y;
        }
#pragma unroll
        for (int off = 4; off < 64; off <<= 1) {
            acc[0] += __shfl_xor(acc[0], off);
            acc[1] += __shfl_xor(acc[1], off);
            acc[2] += __shfl_xor(acc[2], off);
            acc[3] += __shfl_xor(acc[3], off);
        }
        if (es == 0) {
            float o0 = fmaxf(acc[0] + b0, 0.f);
            float o1 = fmaxf(acc[1] + b1, 0.f);
            float o2 = fmaxf(acc[2] + b2, 0.f);
            float o3 = fmaxf(acc[3] + b3, 0.f);
            H8u pk16;
            pk16.h[0] = __floats2half2_rn(o0, o1);
            pk16.h[1] = __floats2half2_rn(o2, o3);
            *(uint2*)(As + (size_t)node * 16 + cp * 4) = pk16.u;
        }
    }
}

// ============ classifier: out = A16 @ Wc + bc  (A16 slice-major) ======
__global__ __launch_bounds__(256) void classify16(const __half* __restrict__ A,
                                                  const float* __restrict__ Wc,
                                                  const float* __restrict__ bc,
                                                  float* __restrict__ out, int n) {
    int node = blockIdx.x * 4 + (threadIdx.x >> 6);
    if (node >= n) return;
    int lane = threadIdx.x & 63;
    int col = lane * 2;
    int sl = col >> 4, off = col & 15;
    __half2 h2 = *(const __half2*)(A + (size_t)sl * NSL16 + (size_t)node * 16 + off);
    float2 f = __half22float2(h2);
    float o0 = f.x * Wc[col * 2]       + f.y * Wc[(col + 1) * 2];
    float o1 = f.x * Wc[col * 2 + 1]   + f.y * Wc[(col + 1) * 2 + 1];
#pragma unroll
    for (int offx = 32; offx; offx >>= 1) {
        o0 += __shfl_xor(o0, offx);
        o1 += __shfl_xor(o1, offx);
    }
    if (lane == 0) {
        out[(size_t)node * 2 + 0] = o0 + bc[0];
        out[(size_t)node * 2 + 1] = o1 + bc[1];
    }
}

extern "C" void kernel_launch(void* const* d_in, const int* in_sizes, int n_in,
                              void* d_out, int out_size, void* d_ws, size_t ws_size,
                              hipStream_t stream) {
    const float* x   = (const float*)d_in[0];
    const int*   ei  = (const int*)d_in[1];
    const int*   src = ei;
    const int*   dst = ei + NEDGES;
    const float* Ws[3]  = {(const float*)d_in[2], (const float*)d_in[6], (const float*)d_in[10]};
    const float* ass[3] = {(const float*)d_in[3], (const float*)d_in[7], (const float*)d_in[11]};
    const float* ads[3] = {(const float*)d_in[4], (const float*)d_in[8], (const float*)d_in[12]};
    const float* bs[3]  = {(const float*)d_in[5], (const float*)d_in[9], (const float*)d_in[13]};
    const float* Wc = (const float*)d_in[14];
    const float* bc = (const float*)d_in[15];
    float* out = (float*)d_out;

    const int n = NNODES;

    // ---- workspace (~67 MB): h16 | a16 | s | d | selfpk | int tail ----
    __half*   h16  = (__half*)d_ws;                     // N*128 fp16 (slice-major)
    __half*   a16  = h16 + (size_t)n * DIM;             // N*128 fp16 (slice-major)
    float*    sbuf = (float*)(a16 + (size_t)n * DIM);   // N
    float*    dbuf = sbuf + n;                          // N
    unsigned* selfpk = (unsigned*)(dbuf + n);           // N
    int*      rowptr      = (int*)(selfpk + n);         // N+1
    int*      csr_src     = rowptr + n + 1;             // E
    int*      packed      = csr_src + NEDGES;           // E (CSR build; reused as packed2)
    int*      blockcounts = packed + NEDGES;            // NB*NCH
    int*      bbase       = blockcounts + NB * NCH;     // NB+1
    int*      btotal      = bbase + NB + 1;             // NB
    unsigned* packed2     = (unsigned*)packed;

    const int g64       = (n + 63) / 64;
    const int node_grid = (n + 3) / 4;          // 25000
    const int agg_grid  = ((n + 31) / 32) * 8;  // 25000

    // ---- bucket-sort CSR build (once, reused by all 3 layers) ----
    bucket_count<<<NCH, 512, 0, stream>>>(dst, blockcounts);
    bucket_scan_a<<<NB, NCH, 0, stream>>>(blockcounts, btotal);
    bucket_scan_b<<<1, 1024, 0, stream>>>(btotal, bbase);
    bucket_scatter<<<NCH, 512, 0, stream>>>(src, dst, blockcounts, bbase, packed);
    bucket_csr<<<NB, 256, 0, stream>>>(packed, bbase, rowptr, csr_src);

    // ---- 3 GAT layers ----
    for (int layer = 0; layer < 3; ++layer) {
        if (layer == 0)
            gemm_mfma<false><<<g64, 256, 0, stream>>>(x, a16, Ws[0], ass[0], ads[0],
                                                      h16, sbuf, dbuf, n);
        else
            gemm_mfma<true><<<g64, 256, 0, stream>>>(x, a16, Ws[layer], ass[layer], ads[layer],
                                                     h16, sbuf, dbuf, n);
        gat_alpha<<<node_grid, 256, 0, stream>>>(rowptr, csr_src, sbuf, dbuf,
                                                 packed2, selfpk, n);
        gat_agg<<<agg_grid, 256, 0, stream>>>(rowptr, packed2, selfpk, h16,
                                              bs[layer], a16, n);
    }
    classify16<<<node_grid, 256, 0, stream>>>(a16, Wc, bc, out, n);
}

// Round 10
// 624.004 us; speedup vs baseline: 1.4335x; 1.4335x over previous
//
#include <hip/hip_runtime.h>
#include <hip/hip_fp16.h>

#define NNODES 100000
#define NEDGES 1600000
#define DIM 128
#define NB ((NNODES + 63) / 64)          // 1563 buckets of 64 nodes
#define NCH 128                          // scatter blocks / edge chunks
#define CHUNK ((NEDGES + NCH - 1) / NCH) // 12500 edges per chunk
#define EBUF 2560                        // per-bucket LDS edge capacity
#define LSTR 136                         // padded LDS stride (halfs)
#define NSL16 ((size_t)NNODES * 16)      // slice-major slice stride (halfs)

typedef _Float16 f16x8 __attribute__((ext_vector_type(8)));
typedef float f32x4 __attribute__((ext_vector_type(4)));

__device__ __forceinline__ float leaky02(float t) { return t > 0.f ? t : 0.2f * t; }

union H8u { uint2 u; __half2 h[2]; };

// slice-major fp16 feature layout: elem(node, col) = buf[(col>>4)*NSL16 + node*16 + (col&15)]

// ============ MFMA fp16 GEMM + fused attention dots ==================
template <bool XF16>
__global__ __launch_bounds__(256) void gemm_mfma(const float* __restrict__ X,
                                                 const __half* __restrict__ X16,
                                                 const float* __restrict__ W,
                                                 const float* __restrict__ as_,
                                                 const float* __restrict__ ad_,
                                                 __half* __restrict__ H,
                                                 float* __restrict__ s,
                                                 float* __restrict__ d, int n) {
    __shared__ __half As[64][LSTR];
    __shared__ __half Wt[128][LSTR];
    int t = threadIdx.x;
    int brow = blockIdx.x * 64;

    if (XF16) {
        for (int i = t; i < 64 * 16; i += 256) {
            int r = i >> 4, c8 = (i & 15) * 8;
            int gr = brow + r;
            int sl = c8 >> 4, off = c8 & 15;
            uint4 v = (gr < n) ? *(const uint4*)(X16 + (size_t)sl * NSL16 + (size_t)gr * 16 + off)
                               : make_uint4(0u, 0u, 0u, 0u);
            *(uint4*)&As[r][c8] = v;
        }
    } else {
        for (int i = t; i < 64 * 32; i += 256) {
            int r = i >> 5, c4 = (i & 31) * 4;
            int gr = brow + r;
            float4 v = (gr < n) ? *(const float4*)(X + (size_t)gr * 128 + c4)
                                : make_float4(0.f, 0.f, 0.f, 0.f);
            As[r][c4 + 0] = __float2half_rn(v.x);
            As[r][c4 + 1] = __float2half_rn(v.y);
            As[r][c4 + 2] = __float2half_rn(v.z);
            As[r][c4 + 3] = __float2half_rn(v.w);
        }
    }
    for (int i = t; i < 128 * 32; i += 256) {
        int k = i >> 5, n4 = (i & 31) * 4;
        float4 wv = *(const float4*)(W + k * 128 + n4);
        Wt[n4 + 0][k] = __float2half_rn(wv.x);
        Wt[n4 + 1][k] = __float2half_rn(wv.y);
        Wt[n4 + 2][k] = __float2half_rn(wv.z);
        Wt[n4 + 3][k] = __float2half_rn(wv.w);
    }
    __syncthreads();

    int wid  = t >> 6;
    int lane = t & 63;
    int lrow = lane & 15;
    int lkg  = lane >> 4;
    int r0   = wid * 16;

    f32x4 acc[8] = {};
#pragma unroll
    for (int kk = 0; kk < 128; kk += 32) {
        f16x8 af = *(const f16x8*)&As[r0 + lrow][kk + lkg * 8];
#pragma unroll
        for (int ct = 0; ct < 8; ++ct) {
            f16x8 bf = *(const f16x8*)&Wt[ct * 16 + lrow][kk + lkg * 8];
            acc[ct] = __builtin_amdgcn_mfma_f32_16x16x32_f16(af, bf, acc[ct], 0, 0, 0);
        }
    }

    float sp[4] = {0.f, 0.f, 0.f, 0.f};
    float dp[4] = {0.f, 0.f, 0.f, 0.f};
#pragma unroll
    for (int ct = 0; ct < 8; ++ct) {
        float a_s = as_[ct * 16 + lrow];
        float a_d = ad_[ct * 16 + lrow];
#pragma unroll
        for (int j = 0; j < 4; ++j) {
            sp[j] += acc[ct][j] * a_s;
            dp[j] += acc[ct][j] * a_d;
        }
    }
#pragma unroll
    for (int j = 0; j < 4; ++j) {
        int gr = brow + r0 + lkg * 4 + j;
        if (gr < n) {
#pragma unroll
            for (int ct = 0; ct < 8; ++ct)   // slice-major store: slice == ct
                H[(size_t)ct * NSL16 + (size_t)gr * 16 + lrow] = __float2half_rn(acc[ct][j]);
        }
    }
#pragma unroll
    for (int off = 1; off < 16; off <<= 1)
#pragma unroll
        for (int j = 0; j < 4; ++j) {
            sp[j] += __shfl_xor(sp[j], off);
            dp[j] += __shfl_xor(dp[j], off);
        }
    if (lrow == 0)
#pragma unroll
        for (int j = 0; j < 4; ++j) {
            int gr = brow + r0 + lkg * 4 + j;
            if (gr < n) { s[gr] = sp[j]; d[gr] = dp[j]; }
        }
}

// ============ bucket-sort CSR build (no global atomics) =============
__global__ __launch_bounds__(512) void bucket_count(const int* __restrict__ dst,
                                                    int* __restrict__ blockcounts) {
    __shared__ int hist[NB];
    int b = blockIdx.x, t = threadIdx.x;
    for (int i = t; i < NB; i += 512) hist[i] = 0;
    __syncthreads();
    int e0 = b * CHUNK, e1 = min(NEDGES, e0 + CHUNK);
    for (int e = e0 + t; e < e1; e += 512)
        atomicAdd(&hist[dst[e] >> 6], 1);
    __syncthreads();
    for (int i = t; i < NB; i += 512)
        blockcounts[i * NCH + b] = hist[i];
}

__global__ __launch_bounds__(NCH) void bucket_scan_a(int* __restrict__ blockcounts,
                                                     int* __restrict__ btotal) {
    int bin = blockIdx.x, t = threadIdx.x;
    int v = blockcounts[bin * NCH + t];
    int incl = v;
#pragma unroll
    for (int off = 1; off < 64; off <<= 1) {
        int u = __shfl_up(incl, off, 64);
        if ((t & 63) >= off) incl += u;
    }
    __shared__ int wsum;
    if (t == 63) wsum = incl;
    __syncthreads();
    int excl = incl - v + ((t >= 64) ? wsum : 0);
    blockcounts[bin * NCH + t] = excl;
    if (t == NCH - 1) btotal[bin] = excl + v;
}

__global__ __launch_bounds__(1024) void bucket_scan_b(const int* __restrict__ btotal,
                                                      int* __restrict__ bbase) {
    __shared__ int ts[2][1024];
    int t = threadIdx.x;
    int b0 = t * 2;
    int c0 = (b0 < NB)     ? btotal[b0]     : 0;
    int c1 = (b0 + 1 < NB) ? btotal[b0 + 1] : 0;
    int sum = c0 + c1;
    ts[0][t] = sum;
    __syncthreads();
    int sb = 0;
    for (int off = 1; off < 1024; off <<= 1) {
        int v = ts[sb][t] + ((t >= off) ? ts[sb][t - off] : 0);
        ts[sb ^ 1][t] = v;
        sb ^= 1;
        __syncthreads();
    }
    int excl = ts[sb][t] - sum;
    if (b0 < NB)     bbase[b0]     = excl;
    if (b0 + 1 < NB) bbase[b0 + 1] = excl + c0;
    if (t == 1023) bbase[NB] = ts[sb][1023];
}

__global__ __launch_bounds__(512) void bucket_scatter(const int* __restrict__ src,
                                                      const int* __restrict__ dst,
                                                      const int* __restrict__ blockcounts,
                                                      const int* __restrict__ bbase,
                                                      int* __restrict__ packed) {
    __shared__ int cur[NB];
    int b = blockIdx.x, t = threadIdx.x;
    for (int i = t; i < NB; i += 512) cur[i] = bbase[i] + blockcounts[i * NCH + b];
    __syncthreads();
    int e0 = b * CHUNK, e1 = min(NEDGES, e0 + CHUNK);
    for (int e = e0 + t; e < e1; e += 512) {
        int dv = dst[e];
        int bin = dv >> 6;
        int p = atomicAdd(&cur[bin], 1);
        packed[p] = ((dv & 63) << 17) | src[e];
    }
}

__global__ __launch_bounds__(256) void bucket_csr(const int* __restrict__ packed,
                                                  const int* __restrict__ bbase,
                                                  int* __restrict__ rowptr,
                                                  int* __restrict__ csr_src) {
    __shared__ int ebuf[EBUF];
    __shared__ int hist[64], cur[64];
    int i = blockIdx.x, t = threadIdx.x;
    int base = bbase[i], cnt = bbase[i + 1] - base;
    bool inl = (cnt <= EBUF);
    if (inl) for (int j = t; j < cnt; j += 256) ebuf[j] = packed[base + j];
    if (t < 64) hist[t] = 0;
    __syncthreads();
    for (int j = t; j < cnt; j += 256) {
        int v = inl ? ebuf[j] : packed[base + j];
        atomicAdd(&hist[v >> 17], 1);
    }
    __syncthreads();
    if (t < 64) {
        int h = hist[t];
        int incl = h;
#pragma unroll
        for (int off = 1; off < 64; off <<= 1) {
            int u = __shfl_up(incl, off, 64);
            if (t >= off) incl += u;
        }
        int ex = incl - h;
        cur[t] = ex;
        int node = i * 64 + t;
        if (node <= NNODES) rowptr[node] = base + ex;
    }
    __syncthreads();
    for (int j = t; j < cnt; j += 256) {
        int v = inl ? ebuf[j] : packed[base + j];
        int off = atomicAdd(&cur[v >> 17], 1);
        csr_src[base + off] = v & 0x1FFFF;
    }
}

// ============ per-edge normalized attention weights, packed u32 =======
// packed2[e] = (src << 15) | round(alpha * 32767);  selfpk[n] likewise.
__global__ __launch_bounds__(256) void gat_alpha(const int* __restrict__ rowptr,
                                                 const int* __restrict__ csr,
                                                 const float* __restrict__ s,
                                                 const float* __restrict__ d,
                                                 unsigned* __restrict__ packed2,
                                                 unsigned* __restrict__ selfpk, int n) {
    int node = blockIdx.x * 4 + (threadIdx.x >> 6);
    if (node >= n) return;
    int lane = threadIdx.x & 63;
    int base = rowptr[node];
    int deg  = rowptr[node + 1] - base;
    float dnode = d[node], snode = s[node];

    if (deg < 64) {
        int cnt = deg + 1;
        int si  = (lane < deg) ? csr[base + lane] : node;
        float sv = (lane < deg) ? s[si] : snode;
        float lv = leaky02(sv + dnode);
        float lm = (lane < cnt) ? lv : -1e30f;
#pragma unroll
        for (int off = 32; off; off >>= 1) lm = fmaxf(lm, __shfl_xor(lm, off));
        float w = (lane < cnt) ? expf(lv - lm) : 0.f;
        float denom = w;
#pragma unroll
        for (int off = 32; off; off >>= 1) denom += __shfl_xor(denom, off);
        unsigned q = (unsigned)__float2int_rn(w / denom * 32767.f);
        unsigned pk = ((unsigned)si << 15) | q;
        if (lane < deg)        packed2[base + lane] = pk;
        else if (lane == deg)  selfpk[node] = pk;
    } else {
        float m = -1e30f;
        for (int c = 0; c <= deg; c += 64) {
            int idx = c + lane;
            float lv = -1e30f;
            if (idx < deg)       lv = leaky02(s[csr[base + idx]] + dnode);
            else if (idx == deg) lv = leaky02(snode + dnode);
            m = fmaxf(m, lv);
        }
#pragma unroll
        for (int off = 32; off; off >>= 1) m = fmaxf(m, __shfl_xor(m, off));
        float denom = 0.f;
        for (int c = 0; c <= deg; c += 64) {
            int idx = c + lane;
            if (idx < deg)       denom += expf(leaky02(s[csr[base + idx]] + dnode) - m);
            else if (idx == deg) denom += expf(leaky02(snode + dnode) - m);
        }
#pragma unroll
        for (int off = 32; off; off >>= 1) denom += __shfl_xor(denom, off);
        for (int c = 0; c <= deg; c += 64) {
            int idx = c + lane;
            if (idx < deg) {
                int si = csr[base + idx];
                float w = expf(leaky02(s[si] + dnode) - m);
                packed2[base + idx] = ((unsigned)si << 15) |
                                      (unsigned)__float2int_rn(w / denom * 32767.f);
            } else if (idx == deg) {
                float w = expf(leaky02(snode + dnode) - m);
                selfpk[node] = ((unsigned)node << 15) |
                               (unsigned)__float2int_rn(w / denom * 32767.f);
            }
        }
    }
}

// ============ sliced aggregation, shuffle-free ========================
// slice = blockIdx & 7 -> XCD-local 3.2MB H-slice (L2-resident).
// lane owns (node, col-quad): 64 lanes = 16 nodes x 4 quads; serial edge
// loop per lane, zero cross-lane ops, 512B contiguous store per wave.
__global__ __launch_bounds__(256) void gat_agg(const int* __restrict__ rowptr,
                                               const unsigned* __restrict__ packed2,
                                               const unsigned* __restrict__ selfpk,
                                               const __half* __restrict__ H,
                                               const float* __restrict__ bias,
                                               __half* __restrict__ A16, int n) {
    int sl  = blockIdx.x & 7;
    int blk = blockIdx.x >> 3;           // 64-node block
    int wid = threadIdx.x >> 6;
    int lane = threadIdx.x & 63;
    int nd = lane >> 2;                  // node within wave 0..15
    int cq = lane & 3;                   // col quad 0..3
    int node = blk * 64 + wid * 16 + nd;
    if (node >= n) return;
    const __half* Hs = H + (size_t)sl * NSL16;
    __half* As = A16 + (size_t)sl * NSL16;

    int base = rowptr[node];
    int deg  = rowptr[node + 1] - base;
    f32x4 acc = {0.f, 0.f, 0.f, 0.f};
    for (int e = 0; e <= deg; ++e) {
        unsigned pk = (e < deg) ? packed2[base + e] : selfpk[node];
        float a = (float)(pk & 0x7fffu) * (1.f / 32767.f);
        H8u hv;
        hv.u = *(const uint2*)(Hs + (size_t)(pk >> 15) * 16 + cq * 4);
        float2 a01 = __half22float2(hv.h[0]);
        float2 a23 = __half22float2(hv.h[1]);
        acc[0] += a * a01.x;
        acc[1] += a * a01.y;
        acc[2] += a * a23.x;
        acc[3] += a * a23.y;
    }
    float o0 = fmaxf(acc[0] + bias[sl * 16 + cq * 4 + 0], 0.f);
    float o1 = fmaxf(acc[1] + bias[sl * 16 + cq * 4 + 1], 0.f);
    float o2 = fmaxf(acc[2] + bias[sl * 16 + cq * 4 + 2], 0.f);
    float o3 = fmaxf(acc[3] + bias[sl * 16 + cq * 4 + 3], 0.f);
    H8u pk16;
    pk16.h[0] = __floats2half2_rn(o0, o1);
    pk16.h[1] = __floats2half2_rn(o2, o3);
    *(uint2*)(As + (size_t)node * 16 + cq * 4) = pk16.u;
}

// ============ classifier: out = A16 @ Wc + bc  (A16 slice-major) ======
__global__ __launch_bounds__(256) void classify16(const __half* __restrict__ A,
                                                  const float* __restrict__ Wc,
                                                  const float* __restrict__ bc,
                                                  float* __restrict__ out, int n) {
    int node = blockIdx.x * 4 + (threadIdx.x >> 6);
    if (node >= n) return;
    int lane = threadIdx.x & 63;
    int col = lane * 2;
    int sl = col >> 4, off = col & 15;
    __half2 h2 = *(const __half2*)(A + (size_t)sl * NSL16 + (size_t)node * 16 + off);
    float2 f = __half22float2(h2);
    float o0 = f.x * Wc[col * 2]       + f.y * Wc[(col + 1) * 2];
    float o1 = f.x * Wc[col * 2 + 1]   + f.y * Wc[(col + 1) * 2 + 1];
#pragma unroll
    for (int offx = 32; offx; offx >>= 1) {
        o0 += __shfl_xor(o0, offx);
        o1 += __shfl_xor(o1, offx);
    }
    if (lane == 0) {
        out[(size_t)node * 2 + 0] = o0 + bc[0];
        out[(size_t)node * 2 + 1] = o1 + bc[1];
    }
}

extern "C" void kernel_launch(void* const* d_in, const int* in_sizes, int n_in,
                              void* d_out, int out_size, void* d_ws, size_t ws_size,
                              hipStream_t stream) {
    const float* x   = (const float*)d_in[0];
    const int*   ei  = (const int*)d_in[1];
    const int*   src = ei;
    const int*   dst = ei + NEDGES;
    const float* Ws[3]  = {(const float*)d_in[2], (const float*)d_in[6], (const float*)d_in[10]};
    const float* ass[3] = {(const float*)d_in[3], (const float*)d_in[7], (const float*)d_in[11]};
    const float* ads[3] = {(const float*)d_in[4], (const float*)d_in[8], (const float*)d_in[12]};
    const float* bs[3]  = {(const float*)d_in[5], (const float*)d_in[9], (const float*)d_in[13]};
    const float* Wc = (const float*)d_in[14];
    const float* bc = (const float*)d_in[15];
    float* out = (float*)d_out;

    const int n = NNODES;

    // ---- workspace (~67 MB): h16 | a16 | s | d | selfpk | int tail ----
    __half*   h16  = (__half*)d_ws;                     // N*128 fp16 (slice-major)
    __half*   a16  = h16 + (size_t)n * DIM;             // N*128 fp16 (slice-major)
    float*    sbuf = (float*)(a16 + (size_t)n * DIM);   // N
    float*    dbuf = sbuf + n;                          // N
    unsigned* selfpk = (unsigned*)(dbuf + n);           // N
    int*      rowptr      = (int*)(selfpk + n);         // N+1
    int*      csr_src     = rowptr + n + 1;             // E
    int*      packed      = csr_src + NEDGES;           // E (CSR build; reused as packed2)
    int*      blockcounts = packed + NEDGES;            // NB*NCH
    int*      bbase       = blockcounts + NB * NCH;     // NB+1
    int*      btotal      = bbase + NB + 1;             // NB
    unsigned* packed2     = (unsigned*)packed;

    const int g64       = (n + 63) / 64;
    const int node_grid = (n + 3) / 4;            // 25000
    const int agg_grid  = ((n + 63) / 64) * 8;    // 12504

    // ---- bucket-sort CSR build (once, reused by all 3 layers) ----
    bucket_count<<<NCH, 512, 0, stream>>>(dst, blockcounts);
    bucket_scan_a<<<NB, NCH, 0, stream>>>(blockcounts, btotal);
    bucket_scan_b<<<1, 1024, 0, stream>>>(btotal, bbase);
    bucket_scatter<<<NCH, 512, 0, stream>>>(src, dst, blockcounts, bbase, packed);
    bucket_csr<<<NB, 256, 0, stream>>>(packed, bbase, rowptr, csr_src);

    // ---- 3 GAT layers ----
    for (int layer = 0; layer < 3; ++layer) {
        if (layer == 0)
            gemm_mfma<false><<<g64, 256, 0, stream>>>(x, a16, Ws[0], ass[0], ads[0],
                                                      h16, sbuf, dbuf, n);
        else
            gemm_mfma<true><<<g64, 256, 0, stream>>>(x, a16, Ws[layer], ass[layer], ads[layer],
                                                     h16, sbuf, dbuf, n);
        gat_alpha<<<node_grid, 256, 0, stream>>>(rowptr, csr_src, sbuf, dbuf,
                                                 packed2, selfpk, n);
        gat_agg<<<agg_grid, 256, 0, stream>>>(rowptr, packed2, selfpk, h16,
                                              bs[layer], a16, n);
    }
    classify16<<<node_grid, 256, 0, stream>>>(a16, Wc, bc, out, n);
}

// Round 11
// 512.249 us; speedup vs baseline: 1.7462x; 1.2182x over previous
//
#include <hip/hip_runtime.h>
#include <hip/hip_fp16.h>

#define NNODES 100000
#define NEDGES 1600000
#define DIM 128
#define NB ((NNODES + 63) / 64)          // 1563 buckets of 64 nodes
#define NCH 128                          // scatter blocks / edge chunks
#define CHUNK ((NEDGES + NCH - 1) / NCH) // 12500 edges per chunk
#define EBUF 2560                        // per-bucket LDS edge capacity
#define LSTR 136                         // padded LDS stride (halfs)
#define NSL16 ((size_t)NNODES * 16)      // slice-major slice stride (halfs)

typedef _Float16 f16x8 __attribute__((ext_vector_type(8)));
typedef float f32x4 __attribute__((ext_vector_type(4)));

__device__ __forceinline__ float leaky02(float t) { return t > 0.f ? t : 0.2f * t; }

union H8u { uint2 u; __half2 h[2]; };

// slice-major fp16 feature layout: elem(node, col) = buf[(col>>4)*NSL16 + node*16 + (col&15)]

// ============ MFMA fp16 GEMM + fused attention dots ==================
template <bool XF16>
__global__ __launch_bounds__(256) void gemm_mfma(const float* __restrict__ X,
                                                 const __half* __restrict__ X16,
                                                 const float* __restrict__ W,
                                                 const float* __restrict__ as_,
                                                 const float* __restrict__ ad_,
                                                 __half* __restrict__ H,
                                                 float* __restrict__ s,
                                                 float* __restrict__ d, int n) {
    __shared__ __half As[64][LSTR];
    __shared__ __half Wt[128][LSTR];
    int t = threadIdx.x;
    int brow = blockIdx.x * 64;

    if (XF16) {
        for (int i = t; i < 64 * 16; i += 256) {
            int r = i >> 4, c8 = (i & 15) * 8;
            int gr = brow + r;
            int sl = c8 >> 4, off = c8 & 15;
            uint4 v = (gr < n) ? *(const uint4*)(X16 + (size_t)sl * NSL16 + (size_t)gr * 16 + off)
                               : make_uint4(0u, 0u, 0u, 0u);
            *(uint4*)&As[r][c8] = v;
        }
    } else {
        for (int i = t; i < 64 * 32; i += 256) {
            int r = i >> 5, c4 = (i & 31) * 4;
            int gr = brow + r;
            float4 v = (gr < n) ? *(const float4*)(X + (size_t)gr * 128 + c4)
                                : make_float4(0.f, 0.f, 0.f, 0.f);
            As[r][c4 + 0] = __float2half_rn(v.x);
            As[r][c4 + 1] = __float2half_rn(v.y);
            As[r][c4 + 2] = __float2half_rn(v.z);
            As[r][c4 + 3] = __float2half_rn(v.w);
        }
    }
    for (int i = t; i < 128 * 32; i += 256) {
        int k = i >> 5, n4 = (i & 31) * 4;
        float4 wv = *(const float4*)(W + k * 128 + n4);
        Wt[n4 + 0][k] = __float2half_rn(wv.x);
        Wt[n4 + 1][k] = __float2half_rn(wv.y);
        Wt[n4 + 2][k] = __float2half_rn(wv.z);
        Wt[n4 + 3][k] = __float2half_rn(wv.w);
    }
    __syncthreads();

    int wid  = t >> 6;
    int lane = t & 63;
    int lrow = lane & 15;
    int lkg  = lane >> 4;
    int r0   = wid * 16;

    f32x4 acc[8] = {};
#pragma unroll
    for (int kk = 0; kk < 128; kk += 32) {
        f16x8 af = *(const f16x8*)&As[r0 + lrow][kk + lkg * 8];
#pragma unroll
        for (int ct = 0; ct < 8; ++ct) {
            f16x8 bf = *(const f16x8*)&Wt[ct * 16 + lrow][kk + lkg * 8];
            acc[ct] = __builtin_amdgcn_mfma_f32_16x16x32_f16(af, bf, acc[ct], 0, 0, 0);
        }
    }

    float sp[4] = {0.f, 0.f, 0.f, 0.f};
    float dp[4] = {0.f, 0.f, 0.f, 0.f};
#pragma unroll
    for (int ct = 0; ct < 8; ++ct) {
        float a_s = as_[ct * 16 + lrow];
        float a_d = ad_[ct * 16 + lrow];
#pragma unroll
        for (int j = 0; j < 4; ++j) {
            sp[j] += acc[ct][j] * a_s;
            dp[j] += acc[ct][j] * a_d;
        }
    }
#pragma unroll
    for (int j = 0; j < 4; ++j) {
        int gr = brow + r0 + lkg * 4 + j;
        if (gr < n) {
#pragma unroll
            for (int ct = 0; ct < 8; ++ct)   // slice-major store: slice == ct
                H[(size_t)ct * NSL16 + (size_t)gr * 16 + lrow] = __float2half_rn(acc[ct][j]);
        }
    }
#pragma unroll
    for (int off = 1; off < 16; off <<= 1)
#pragma unroll
        for (int j = 0; j < 4; ++j) {
            sp[j] += __shfl_xor(sp[j], off);
            dp[j] += __shfl_xor(dp[j], off);
        }
    if (lrow == 0)
#pragma unroll
        for (int j = 0; j < 4; ++j) {
            int gr = brow + r0 + lkg * 4 + j;
            if (gr < n) { s[gr] = sp[j]; d[gr] = dp[j]; }
        }
}

// ============ bucket-sort CSR build (no global atomics) =============
__global__ __launch_bounds__(512) void bucket_count(const int* __restrict__ dst,
                                                    int* __restrict__ blockcounts) {
    __shared__ int hist[NB];
    int b = blockIdx.x, t = threadIdx.x;
    for (int i = t; i < NB; i += 512) hist[i] = 0;
    __syncthreads();
    int e0 = b * CHUNK, e1 = min(NEDGES, e0 + CHUNK);
    for (int e = e0 + t; e < e1; e += 512)
        atomicAdd(&hist[dst[e] >> 6], 1);
    __syncthreads();
    for (int i = t; i < NB; i += 512)
        blockcounts[i * NCH + b] = hist[i];
}

__global__ __launch_bounds__(NCH) void bucket_scan_a(int* __restrict__ blockcounts,
                                                     int* __restrict__ btotal) {
    int bin = blockIdx.x, t = threadIdx.x;
    int v = blockcounts[bin * NCH + t];
    int incl = v;
#pragma unroll
    for (int off = 1; off < 64; off <<= 1) {
        int u = __shfl_up(incl, off, 64);
        if ((t & 63) >= off) incl += u;
    }
    __shared__ int wsum;
    if (t == 63) wsum = incl;
    __syncthreads();
    int excl = incl - v + ((t >= 64) ? wsum : 0);
    blockcounts[bin * NCH + t] = excl;
    if (t == NCH - 1) btotal[bin] = excl + v;
}

__global__ __launch_bounds__(1024) void bucket_scan_b(const int* __restrict__ btotal,
                                                      int* __restrict__ bbase) {
    __shared__ int ts[2][1024];
    int t = threadIdx.x;
    int b0 = t * 2;
    int c0 = (b0 < NB)     ? btotal[b0]     : 0;
    int c1 = (b0 + 1 < NB) ? btotal[b0 + 1] : 0;
    int sum = c0 + c1;
    ts[0][t] = sum;
    __syncthreads();
    int sb = 0;
    for (int off = 1; off < 1024; off <<= 1) {
        int v = ts[sb][t] + ((t >= off) ? ts[sb][t - off] : 0);
        ts[sb ^ 1][t] = v;
        sb ^= 1;
        __syncthreads();
    }
    int excl = ts[sb][t] - sum;
    if (b0 < NB)     bbase[b0]     = excl;
    if (b0 + 1 < NB) bbase[b0 + 1] = excl + c0;
    if (t == 1023) bbase[NB] = ts[sb][1023];
}

__global__ __launch_bounds__(512) void bucket_scatter(const int* __restrict__ src,
                                                      const int* __restrict__ dst,
                                                      const int* __restrict__ blockcounts,
                                                      const int* __restrict__ bbase,
                                                      int* __restrict__ packed) {
    __shared__ int cur[NB];
    int b = blockIdx.x, t = threadIdx.x;
    for (int i = t; i < NB; i += 512) cur[i] = bbase[i] + blockcounts[i * NCH + b];
    __syncthreads();
    int e0 = b * CHUNK, e1 = min(NEDGES, e0 + CHUNK);
    for (int e = e0 + t; e < e1; e += 512) {
        int dv = dst[e];
        int bin = dv >> 6;
        int p = atomicAdd(&cur[bin], 1);
        packed[p] = ((dv & 63) << 17) | src[e];
    }
}

// pass 4: per-bucket local count/scan -> rowptr + csr_src WITH self-loop
// appended as each node's last slot (csr spans E+N entries).
__global__ __launch_bounds__(256) void bucket_csr(const int* __restrict__ packed,
                                                  const int* __restrict__ bbase,
                                                  int* __restrict__ rowptr,
                                                  int* __restrict__ csr_src) {
    __shared__ int ebuf[EBUF];
    __shared__ int hist[64], cur[64];
    int i = blockIdx.x, t = threadIdx.x;
    int base_in = bbase[i], cnt = bbase[i + 1] - base_in;
    int base_out = base_in + i * 64;          // +64 self slots per full bucket
    bool inl = (cnt <= EBUF);
    if (inl) for (int j = t; j < cnt; j += 256) ebuf[j] = packed[base_in + j];
    if (t < 64) hist[t] = 0;
    __syncthreads();
    for (int j = t; j < cnt; j += 256) {
        int v = inl ? ebuf[j] : packed[base_in + j];
        atomicAdd(&hist[v >> 17], 1);
    }
    __syncthreads();
    if (t < 64) {
        int node = i * 64 + t;
        int h = hist[t];
        int h2 = h + (node < NNODES ? 1 : 0);   // +1 self slot
        int incl = h2;
#pragma unroll
        for (int off = 1; off < 64; off <<= 1) {
            int u = __shfl_up(incl, off, 64);
            if (t >= off) incl += u;
        }
        int ex = incl - h2;
        cur[t] = ex;
        if (node <= NNODES) rowptr[node] = base_out + ex;
        if (node < NNODES) csr_src[base_out + ex + h] = node;  // self at end
    }
    __syncthreads();
    for (int j = t; j < cnt; j += 256) {
        int v = inl ? ebuf[j] : packed[base_in + j];
        int off = atomicAdd(&cur[v >> 17], 1);
        csr_src[base_out + off] = v & 0x1FFFF;
    }
}

// ============ per-edge normalized attention weights, packed u32 =======
// csr includes the self edge -> fully uniform. packed2[e] = (src<<15)|q15(alpha)
__global__ __launch_bounds__(256) void gat_alpha(const int* __restrict__ rowptr,
                                                 const int* __restrict__ csr,
                                                 const float* __restrict__ s,
                                                 const float* __restrict__ d,
                                                 unsigned* __restrict__ packed2, int n) {
    int node = blockIdx.x * 4 + (threadIdx.x >> 6);
    if (node >= n) return;
    int lane = threadIdx.x & 63;
    int base = rowptr[node];
    int cnt  = rowptr[node + 1] - base;      // deg + 1 (self included)
    float dnode = d[node];

    if (cnt <= 64) {
        int si = csr[base + min(lane, cnt - 1)];
        float lv = leaky02(s[si] + dnode);
        float lm = (lane < cnt) ? lv : -1e30f;
#pragma unroll
        for (int off = 32; off; off >>= 1) lm = fmaxf(lm, __shfl_xor(lm, off));
        float w = (lane < cnt) ? expf(lv - lm) : 0.f;
        float denom = w;
#pragma unroll
        for (int off = 32; off; off >>= 1) denom += __shfl_xor(denom, off);
        if (lane < cnt)
            packed2[base + lane] = ((unsigned)si << 15) |
                                   (unsigned)__float2int_rn(w / denom * 32767.f);
    } else {
        float m = -1e30f;
        for (int c = 0; c < cnt; c += 64) {
            int idx = c + lane;
            float lv = (idx < cnt) ? leaky02(s[csr[base + idx]] + dnode) : -1e30f;
            m = fmaxf(m, lv);
        }
#pragma unroll
        for (int off = 32; off; off >>= 1) m = fmaxf(m, __shfl_xor(m, off));
        float denom = 0.f;
        for (int c = 0; c < cnt; c += 64) {
            int idx = c + lane;
            if (idx < cnt) denom += expf(leaky02(s[csr[base + idx]] + dnode) - m);
        }
#pragma unroll
        for (int off = 32; off; off >>= 1) denom += __shfl_xor(denom, off);
        for (int c = 0; c < cnt; c += 64) {
            int idx = c + lane;
            if (idx < cnt) {
                int si = csr[base + idx];
                float w = expf(leaky02(s[si] + dnode) - m);
                packed2[base + idx] = ((unsigned)si << 15) |
                                      (unsigned)__float2int_rn(w / denom * 32767.f);
            }
        }
    }
}

// ============ sliced aggregation, shuffle-free, 4-way MLP =============
// slice = blockIdx & 7 -> XCD-local 3.2MB H-slice (L2-resident).
// lane owns (node, col-quad); 4 independent pk+H chains in flight.
__global__ __launch_bounds__(256) void gat_agg(const int* __restrict__ rowptr,
                                               const unsigned* __restrict__ packed2,
                                               const __half* __restrict__ H,
                                               const float* __restrict__ bias,
                                               __half* __restrict__ A16, int n) {
    int sl  = blockIdx.x & 7;
    int blk = blockIdx.x >> 3;
    int wid = threadIdx.x >> 6;
    int lane = threadIdx.x & 63;
    int nd = lane >> 2;
    int cq = lane & 3;
    int node = blk * 64 + wid * 16 + nd;
    if (node >= n) return;
    const __half* Hs = H + (size_t)sl * NSL16 + cq * 4;
    __half* As = A16 + (size_t)sl * NSL16;

    int base = rowptr[node];
    int cnt  = rowptr[node + 1] - base;      // deg + 1
    const unsigned* p = packed2 + base;
    f32x4 acc = {0.f, 0.f, 0.f, 0.f};
    int iters = (cnt + 3) >> 2;
    int e = 0;
    for (int it = 0; it < iters; ++it, e += 4) {
        int c1 = min(e + 1, cnt - 1), c2 = min(e + 2, cnt - 1), c3 = min(e + 3, cnt - 1);
        unsigned pk0 = p[e], pk1 = p[c1], pk2 = p[c2], pk3 = p[c3];
        float a0 = (float)(pk0 & 0x7fffu);
        float a1 = (e + 1 < cnt) ? (float)(pk1 & 0x7fffu) : 0.f;
        float a2 = (e + 2 < cnt) ? (float)(pk2 & 0x7fffu) : 0.f;
        float a3 = (e + 3 < cnt) ? (float)(pk3 & 0x7fffu) : 0.f;
        H8u h0, h1, h2, h3;
        h0.u = *(const uint2*)(Hs + (size_t)(pk0 >> 15) * 16);
        h1.u = *(const uint2*)(Hs + (size_t)(pk1 >> 15) * 16);
        h2.u = *(const uint2*)(Hs + (size_t)(pk2 >> 15) * 16);
        h3.u = *(const uint2*)(Hs + (size_t)(pk3 >> 15) * 16);
        float2 p00 = __half22float2(h0.h[0]), p01 = __half22float2(h0.h[1]);
        float2 p10 = __half22float2(h1.h[0]), p11 = __half22float2(h1.h[1]);
        float2 p20 = __half22float2(h2.h[0]), p21 = __half22float2(h2.h[1]);
        float2 p30 = __half22float2(h3.h[0]), p31 = __half22float2(h3.h[1]);
        acc[0] += a0 * p00.x + a1 * p10.x + a2 * p20.x + a3 * p30.x;
        acc[1] += a0 * p00.y + a1 * p10.y + a2 * p20.y + a3 * p30.y;
        acc[2] += a0 * p01.x + a1 * p11.x + a2 * p21.x + a3 * p31.x;
        acc[3] += a0 * p01.y + a1 * p11.y + a2 * p21.y + a3 * p31.y;
    }
    const float scale = 1.f / 32767.f;
    float o0 = fmaxf(acc[0] * scale + bias[sl * 16 + cq * 4 + 0], 0.f);
    float o1 = fmaxf(acc[1] * scale + bias[sl * 16 + cq * 4 + 1], 0.f);
    float o2 = fmaxf(acc[2] * scale + bias[sl * 16 + cq * 4 + 2], 0.f);
    float o3 = fmaxf(acc[3] * scale + bias[sl * 16 + cq * 4 + 3], 0.f);
    H8u pk16;
    pk16.h[0] = __floats2half2_rn(o0, o1);
    pk16.h[1] = __floats2half2_rn(o2, o3);
    *(uint2*)(As + (size_t)node * 16 + cq * 4) = pk16.u;
}

// ============ classifier: out = A16 @ Wc + bc  (A16 slice-major) ======
__global__ __launch_bounds__(256) void classify16(const __half* __restrict__ A,
                                                  const float* __restrict__ Wc,
                                                  const float* __restrict__ bc,
                                                  float* __restrict__ out, int n) {
    int node = blockIdx.x * 4 + (threadIdx.x >> 6);
    if (node >= n) return;
    int lane = threadIdx.x & 63;
    int col = lane * 2;
    int sl = col >> 4, off = col & 15;
    __half2 h2 = *(const __half2*)(A + (size_t)sl * NSL16 + (size_t)node * 16 + off);
    float2 f = __half22float2(h2);
    float o0 = f.x * Wc[col * 2]       + f.y * Wc[(col + 1) * 2];
    float o1 = f.x * Wc[col * 2 + 1]   + f.y * Wc[(col + 1) * 2 + 1];
#pragma unroll
    for (int offx = 32; offx; offx >>= 1) {
        o0 += __shfl_xor(o0, offx);
        o1 += __shfl_xor(o1, offx);
    }
    if (lane == 0) {
        out[(size_t)node * 2 + 0] = o0 + bc[0];
        out[(size_t)node * 2 + 1] = o1 + bc[1];
    }
}

extern "C" void kernel_launch(void* const* d_in, const int* in_sizes, int n_in,
                              void* d_out, int out_size, void* d_ws, size_t ws_size,
                              hipStream_t stream) {
    const float* x   = (const float*)d_in[0];
    const int*   ei  = (const int*)d_in[1];
    const int*   src = ei;
    const int*   dst = ei + NEDGES;
    const float* Ws[3]  = {(const float*)d_in[2], (const float*)d_in[6], (const float*)d_in[10]};
    const float* ass[3] = {(const float*)d_in[3], (const float*)d_in[7], (const float*)d_in[11]};
    const float* ads[3] = {(const float*)d_in[4], (const float*)d_in[8], (const float*)d_in[12]};
    const float* bs[3]  = {(const float*)d_in[5], (const float*)d_in[9], (const float*)d_in[13]};
    const float* Wc = (const float*)d_in[14];
    const float* bc = (const float*)d_in[15];
    float* out = (float*)d_out;

    const int n = NNODES;

    // ---- workspace (~81 MB): h16 | a16 | s | d | rowptr | csr | packed2 | packed | scan
    __half*   h16  = (__half*)d_ws;                     // N*128 fp16 (slice-major)
    __half*   a16  = h16 + (size_t)n * DIM;             // N*128 fp16 (slice-major)
    float*    sbuf = (float*)(a16 + (size_t)n * DIM);   // N
    float*    dbuf = sbuf + n;                          // N
    int*      rowptr      = (int*)(dbuf + n);           // N+1
    int*      csr_src     = rowptr + n + 1;             // E+N (self-loops inline)
    unsigned* packed2     = (unsigned*)(csr_src + NEDGES + n);  // E+N
    int*      packed      = (int*)(packed2 + NEDGES + n);       // E (build temp)
    int*      blockcounts = packed + NEDGES;            // NB*NCH
    int*      bbase       = blockcounts + NB * NCH;     // NB+1
    int*      btotal      = bbase + NB + 1;             // NB

    const int g64       = (n + 63) / 64;
    const int node_grid = (n + 3) / 4;            // 25000
    const int agg_grid  = ((n + 63) / 64) * 8;    // 12504

    // ---- bucket-sort CSR build (once, reused by all 3 layers) ----
    bucket_count<<<NCH, 512, 0, stream>>>(dst, blockcounts);
    bucket_scan_a<<<NB, NCH, 0, stream>>>(blockcounts, btotal);
    bucket_scan_b<<<1, 1024, 0, stream>>>(btotal, bbase);
    bucket_scatter<<<NCH, 512, 0, stream>>>(src, dst, blockcounts, bbase, packed);
    bucket_csr<<<NB, 256, 0, stream>>>(packed, bbase, rowptr, csr_src);

    // ---- 3 GAT layers ----
    for (int layer = 0; layer < 3; ++layer) {
        if (layer == 0)
            gemm_mfma<false><<<g64, 256, 0, stream>>>(x, a16, Ws[0], ass[0], ads[0],
                                                      h16, sbuf, dbuf, n);
        else
            gemm_mfma<true><<<g64, 256, 0, stream>>>(x, a16, Ws[layer], ass[layer], ads[layer],
                                                     h16, sbuf, dbuf, n);
        gat_alpha<<<node_grid, 256, 0, stream>>>(rowptr, csr_src, sbuf, dbuf, packed2, n);
        gat_agg<<<agg_grid, 256, 0, stream>>>(rowptr, packed2, h16, bs[layer], a16, n);
    }
    classify16<<<node_grid, 256, 0, stream>>>(a16, Wc, bc, out, n);
}

// Round 12
// 431.920 us; speedup vs baseline: 2.0710x; 1.1860x over previous
//
#include <hip/hip_runtime.h>
#include <hip/hip_fp16.h>

#define NNODES 100000
#define NEDGES 1600000
#define DIM 128
#define NB ((NNODES + 63) / 64)          // 1563 buckets of 64 nodes
#define NCH 128                          // scatter blocks / edge chunks
#define CHUNK ((NEDGES + NCH - 1) / NCH) // 12500 edges per chunk
#define EBUF 2560                        // per-bucket LDS edge capacity
#define LSTR 136                         // padded LDS stride (halfs)
#define NSL16 ((size_t)NNODES * 16)      // slice-major slice stride (halfs)
#define CSRSZ (NEDGES + NB * 256 + 64)   // padded csr/packed2 capacity

typedef _Float16 f16x8 __attribute__((ext_vector_type(8)));
typedef float f32x4 __attribute__((ext_vector_type(4)));

__device__ __forceinline__ float leaky02(float t) { return t > 0.f ? t : 0.2f * t; }

union H8u { uint2 u; __half2 h[2]; };

// slice-major fp16 feature layout: elem(node, col) = buf[(col>>4)*NSL16 + node*16 + (col&15)]

// ============ one-time W pre-convert: wt16[l][n][k] = fp16(W_l[k][n]) ==
__global__ __launch_bounds__(256) void wprep(const float* __restrict__ W0,
                                             const float* __restrict__ W1,
                                             const float* __restrict__ W2,
                                             __half* __restrict__ wt) {
    int idx = blockIdx.x * 256 + threadIdx.x;
    if (idx >= 3 * 128 * 128) return;
    int l = idx >> 14, rem = idx & 16383;
    int nn = rem >> 7, k = rem & 127;
    const float* W = (l == 0) ? W0 : ((l == 1) ? W1 : W2);
    wt[idx] = __float2half_rn(W[k * 128 + nn]);
}

// ============ MFMA fp16 GEMM + fused attention dots ==================
// block: 64 rows x 128 cols, 4 waves; wave: 16 rows x 128 cols.
// C: acc[ct][j] = H[row=(lane>>4)*4+j][col=ct*16+(lane&15)]  (m89-verified)
template <bool XF16>
__global__ __launch_bounds__(256) void gemm_mfma(const float* __restrict__ X,
                                                 const __half* __restrict__ X16,
                                                 const __half* __restrict__ wt16,
                                                 const float* __restrict__ as_,
                                                 const float* __restrict__ ad_,
                                                 __half* __restrict__ H,
                                                 float* __restrict__ s,
                                                 float* __restrict__ d, int n) {
    __shared__ __half As[64][LSTR];
    __shared__ __half Wt[128][LSTR];
    int t = threadIdx.x;
    int brow = blockIdx.x * 64;

    if (XF16) {
        for (int i = t; i < 64 * 16; i += 256) {
            int r = i >> 4, c8 = (i & 15) * 8;
            int gr = brow + r;
            int sl = c8 >> 4, off = c8 & 15;
            uint4 v = (gr < n) ? *(const uint4*)(X16 + (size_t)sl * NSL16 + (size_t)gr * 16 + off)
                               : make_uint4(0u, 0u, 0u, 0u);
            *(uint4*)&As[r][c8] = v;
        }
    } else {
        for (int i = t; i < 64 * 32; i += 256) {
            int r = i >> 5, c4 = (i & 31) * 4;
            int gr = brow + r;
            float4 v = (gr < n) ? *(const float4*)(X + (size_t)gr * 128 + c4)
                                : make_float4(0.f, 0.f, 0.f, 0.f);
            As[r][c4 + 0] = __float2half_rn(v.x);
            As[r][c4 + 1] = __float2half_rn(v.y);
            As[r][c4 + 2] = __float2half_rn(v.z);
            As[r][c4 + 3] = __float2half_rn(v.w);
        }
    }
    // stage pre-converted W^T: plain uint4 copy (no cvt)
    for (int i = t; i < 128 * 16; i += 256) {
        int r = i >> 4, c8 = (i & 15) * 8;
        *(uint4*)&Wt[r][c8] = *(const uint4*)(wt16 + r * 128 + c8);
    }
    __syncthreads();

    int wid  = t >> 6;
    int lane = t & 63;
    int lrow = lane & 15;
    int lkg  = lane >> 4;
    int r0   = wid * 16;

    f32x4 acc[8] = {};
#pragma unroll
    for (int kk = 0; kk < 128; kk += 32) {
        f16x8 af = *(const f16x8*)&As[r0 + lrow][kk + lkg * 8];
#pragma unroll
        for (int ct = 0; ct < 8; ++ct) {
            f16x8 bf = *(const f16x8*)&Wt[ct * 16 + lrow][kk + lkg * 8];
            acc[ct] = __builtin_amdgcn_mfma_f32_16x16x32_f16(af, bf, acc[ct], 0, 0, 0);
        }
    }

    float sp[4] = {0.f, 0.f, 0.f, 0.f};
    float dp[4] = {0.f, 0.f, 0.f, 0.f};
#pragma unroll
    for (int ct = 0; ct < 8; ++ct) {
        float a_s = as_[ct * 16 + lrow];
        float a_d = ad_[ct * 16 + lrow];
#pragma unroll
        for (int j = 0; j < 4; ++j) {
            sp[j] += acc[ct][j] * a_s;
            dp[j] += acc[ct][j] * a_d;
        }
    }
#pragma unroll
    for (int j = 0; j < 4; ++j) {
        int gr = brow + r0 + lkg * 4 + j;
        if (gr < n) {
#pragma unroll
            for (int ct = 0; ct < 8; ++ct)   // slice-major store: slice == ct
                H[(size_t)ct * NSL16 + (size_t)gr * 16 + lrow] = __float2half_rn(acc[ct][j]);
        }
    }
#pragma unroll
    for (int off = 1; off < 16; off <<= 1)
#pragma unroll
        for (int j = 0; j < 4; ++j) {
            sp[j] += __shfl_xor(sp[j], off);
            dp[j] += __shfl_xor(dp[j], off);
        }
    if (lrow == 0)
#pragma unroll
        for (int j = 0; j < 4; ++j) {
            int gr = brow + r0 + lkg * 4 + j;
            if (gr < n) { s[gr] = sp[j]; d[gr] = dp[j]; }
        }
}

// ============ bucket-sort CSR build (no global atomics) =============
__global__ __launch_bounds__(512) void bucket_count(const int* __restrict__ dst,
                                                    int* __restrict__ blockcounts) {
    __shared__ int hist[NB];
    int b = blockIdx.x, t = threadIdx.x;
    for (int i = t; i < NB; i += 512) hist[i] = 0;
    __syncthreads();
    int e0 = b * CHUNK, e1 = min(NEDGES, e0 + CHUNK);
    for (int e = e0 + t; e < e1; e += 512)
        atomicAdd(&hist[dst[e] >> 6], 1);
    __syncthreads();
    for (int i = t; i < NB; i += 512)
        blockcounts[i * NCH + b] = hist[i];
}

__global__ __launch_bounds__(NCH) void bucket_scan_a(int* __restrict__ blockcounts,
                                                     int* __restrict__ btotal) {
    int bin = blockIdx.x, t = threadIdx.x;
    int v = blockcounts[bin * NCH + t];
    int incl = v;
#pragma unroll
    for (int off = 1; off < 64; off <<= 1) {
        int u = __shfl_up(incl, off, 64);
        if ((t & 63) >= off) incl += u;
    }
    __shared__ int wsum;
    if (t == 63) wsum = incl;
    __syncthreads();
    int excl = incl - v + ((t >= 64) ? wsum : 0);
    blockcounts[bin * NCH + t] = excl;
    if (t == NCH - 1) btotal[bin] = excl + v;
}

__global__ __launch_bounds__(1024) void bucket_scan_b(const int* __restrict__ btotal,
                                                      int* __restrict__ bbase) {
    __shared__ int ts[2][1024];
    int t = threadIdx.x;
    int b0 = t * 2;
    int c0 = (b0 < NB)     ? btotal[b0]     : 0;
    int c1 = (b0 + 1 < NB) ? btotal[b0 + 1] : 0;
    int sum = c0 + c1;
    ts[0][t] = sum;
    __syncthreads();
    int sb = 0;
    for (int off = 1; off < 1024; off <<= 1) {
        int v = ts[sb][t] + ((t >= off) ? ts[sb][t - off] : 0);
        ts[sb ^ 1][t] = v;
        sb ^= 1;
        __syncthreads();
    }
    int excl = ts[sb][t] - sum;
    if (b0 < NB)     bbase[b0]     = excl;
    if (b0 + 1 < NB) bbase[b0 + 1] = excl + c0;
    if (t == 1023) bbase[NB] = ts[sb][1023];
}

__global__ __launch_bounds__(512) void bucket_scatter(const int* __restrict__ src,
                                                      const int* __restrict__ dst,
                                                      const int* __restrict__ blockcounts,
                                                      const int* __restrict__ bbase,
                                                      int* __restrict__ packed) {
    __shared__ int cur[NB];
    int b = blockIdx.x, t = threadIdx.x;
    for (int i = t; i < NB; i += 512) cur[i] = bbase[i] + blockcounts[i * NCH + b];
    __syncthreads();
    int e0 = b * CHUNK, e1 = min(NEDGES, e0 + CHUNK);
    for (int e = e0 + t; e < e1; e += 512) {
        int dv = dst[e];
        int bin = dv >> 6;
        int p = atomicAdd(&cur[bin], 1);
        packed[p] = ((dv & 63) << 17) | src[e];
    }
}

// pass 4: per-bucket count/scan -> PADDED csr (slots rounded to x4, 16B-
// aligned bases), self-loop inline as last real entry; exact count in cnts.
__global__ __launch_bounds__(256) void bucket_csr(const int* __restrict__ packed,
                                                  const int* __restrict__ bbase,
                                                  int* __restrict__ rowptr4,
                                                  int* __restrict__ cnts,
                                                  int* __restrict__ csr_src) {
    __shared__ int ebuf[EBUF];
    __shared__ int hist[64], cur[64];
    int i = blockIdx.x, t = threadIdx.x;
    int base_in = bbase[i], cnt = bbase[i + 1] - base_in;
    int pbase = ((base_in + 3) & ~3) + i * 256;   // 4-slot aligned, gap-safe
    bool inl = (cnt <= EBUF);
    if (inl) for (int j = t; j < cnt; j += 256) ebuf[j] = packed[base_in + j];
    if (t < 64) hist[t] = 0;
    __syncthreads();
    for (int j = t; j < cnt; j += 256) {
        int v = inl ? ebuf[j] : packed[base_in + j];
        atomicAdd(&hist[v >> 17], 1);
    }
    __syncthreads();
    if (t < 64) {
        int node = i * 64 + t;
        bool valid = node < NNODES;
        int h = hist[t];
        int c  = h + (valid ? 1 : 0);             // + self
        int c4 = (c + 3) & ~3;
        int incl = c4;
#pragma unroll
        for (int off = 1; off < 64; off <<= 1) {
            int u = __shfl_up(incl, off, 64);
            if (t >= off) incl += u;
        }
        int ex4 = incl - c4;
        cur[t] = pbase + ex4;                     // absolute edge cursor
        if (valid) {
            rowptr4[node] = pbase + ex4;
            cnts[node] = c;
            csr_src[pbase + ex4 + h] = node;      // self at end of real slots
        }
    }
    __syncthreads();
    for (int j = t; j < cnt; j += 256) {
        int v = inl ? ebuf[j] : packed[base_in + j];
        int off = atomicAdd(&cur[v >> 17], 1);
        csr_src[off] = v & 0x1FFFF;
    }
}

// ============ per-edge normalized attention, 32 lanes/node ============
// packed2[slot] = (src<<15)|q15(alpha); pad slots get (node<<15)|0.
__global__ __launch_bounds__(256) void gat_alpha(const int* __restrict__ rowptr4,
                                                 const int* __restrict__ cnts,
                                                 const int* __restrict__ csr,
                                                 const float* __restrict__ s,
                                                 const float* __restrict__ d,
                                                 unsigned* __restrict__ packed2, int n) {
    int node = blockIdx.x * 8 + (threadIdx.x >> 5);
    if (node >= n) return;
    int lane = threadIdx.x & 31;
    int base = rowptr4[node];
    int cnt  = cnts[node];
    int cnt4 = (cnt + 3) & ~3;
    float dnode = d[node];

    if (cnt <= 32) {
        int si = csr[base + min(lane, cnt - 1)];
        float lv = leaky02(s[si] + dnode);
        float lm = (lane < cnt) ? lv : -1e30f;
#pragma unroll
        for (int off = 16; off; off >>= 1) lm = fmaxf(lm, __shfl_xor(lm, off));
        float w = (lane < cnt) ? expf(lv - lm) : 0.f;
        float denom = w;
#pragma unroll
        for (int off = 16; off; off >>= 1) denom += __shfl_xor(denom, off);
        if (lane < cnt)
            packed2[base + lane] = ((unsigned)si << 15) |
                                   (unsigned)__float2int_rn(w / denom * 32767.f);
        else if (lane < cnt4)
            packed2[base + lane] = (unsigned)node << 15;   // sentinel, alpha=0
    } else {
        float m = -1e30f;
        for (int c = 0; c < cnt; c += 32) {
            int idx = c + lane;
            float lv = (idx < cnt) ? leaky02(s[csr[base + idx]] + dnode) : -1e30f;
            m = fmaxf(m, lv);
        }
#pragma unroll
        for (int off = 16; off; off >>= 1) m = fmaxf(m, __shfl_xor(m, off));
        float denom = 0.f;
        for (int c = 0; c < cnt; c += 32) {
            int idx = c + lane;
            if (idx < cnt) denom += expf(leaky02(s[csr[base + idx]] + dnode) - m);
        }
#pragma unroll
        for (int off = 16; off; off >>= 1) denom += __shfl_xor(denom, off);
        for (int c = 0; c < cnt4; c += 32) {
            int idx = c + lane;
            if (idx < cnt) {
                int si = csr[base + idx];
                float w = expf(leaky02(s[si] + dnode) - m);
                packed2[base + idx] = ((unsigned)si << 15) |
                                      (unsigned)__float2int_rn(w / denom * 32767.f);
            } else if (idx < cnt4) {
                packed2[base + idx] = (unsigned)node << 15;
            }
        }
    }
}

// ============ sliced aggregation: branch-free, affine, uint2 pk loads =
// slice = blockIdx & 7 -> XCD-local 3.2MB H-slice (L2-resident).
// lane owns (node, col-quad); sentinel pads make the loop uniform.
__global__ __launch_bounds__(256) void gat_agg(const int* __restrict__ rowptr4,
                                               const int* __restrict__ cnts,
                                               const unsigned* __restrict__ packed2,
                                               const __half* __restrict__ H,
                                               const float* __restrict__ bias,
                                               __half* __restrict__ A16, int n) {
    int sl  = blockIdx.x & 7;
    int blk = blockIdx.x >> 3;
    int wid = threadIdx.x >> 6;
    int lane = threadIdx.x & 63;
    int nd = lane >> 2;
    int cq = lane & 3;
    int node = blk * 64 + wid * 16 + nd;
    if (node >= n) return;
    const __half* Hs = H + (size_t)sl * NSL16 + cq * 4;
    __half* As = A16 + (size_t)sl * NSL16;

    int base  = rowptr4[node];
    int iters = (cnts[node] + 3) >> 2;
    const unsigned* p = packed2 + base;
    f32x4 acc = {0.f, 0.f, 0.f, 0.f};
    for (int it = 0; it < iters; ++it) {
        uint2 qa = *(const uint2*)(p + it * 4);
        uint2 qb = *(const uint2*)(p + it * 4 + 2);
        unsigned pk0 = qa.x, pk1 = qa.y, pk2 = qb.x, pk3 = qb.y;
        float a0 = (float)(pk0 & 0x7fffu);
        float a1 = (float)(pk1 & 0x7fffu);
        float a2 = (float)(pk2 & 0x7fffu);
        float a3 = (float)(pk3 & 0x7fffu);
        H8u h0, h1, h2, h3;
        h0.u = *(const uint2*)(Hs + (size_t)(pk0 >> 15) * 16);
        h1.u = *(const uint2*)(Hs + (size_t)(pk1 >> 15) * 16);
        h2.u = *(const uint2*)(Hs + (size_t)(pk2 >> 15) * 16);
        h3.u = *(const uint2*)(Hs + (size_t)(pk3 >> 15) * 16);
        float2 p00 = __half22float2(h0.h[0]), p01 = __half22float2(h0.h[1]);
        float2 p10 = __half22float2(h1.h[0]), p11 = __half22float2(h1.h[1]);
        float2 p20 = __half22float2(h2.h[0]), p21 = __half22float2(h2.h[1]);
        float2 p30 = __half22float2(h3.h[0]), p31 = __half22float2(h3.h[1]);
        acc[0] += a0 * p00.x + a1 * p10.x + a2 * p20.x + a3 * p30.x;
        acc[1] += a0 * p00.y + a1 * p10.y + a2 * p20.y + a3 * p30.y;
        acc[2] += a0 * p01.x + a1 * p11.x + a2 * p21.x + a3 * p31.x;
        acc[3] += a0 * p01.y + a1 * p11.y + a2 * p21.y + a3 * p31.y;
    }
    const float scale = 1.f / 32767.f;
    float o0 = fmaxf(acc[0] * scale + bias[sl * 16 + cq * 4 + 0], 0.f);
    float o1 = fmaxf(acc[1] * scale + bias[sl * 16 + cq * 4 + 1], 0.f);
    float o2 = fmaxf(acc[2] * scale + bias[sl * 16 + cq * 4 + 2], 0.f);
    float o3 = fmaxf(acc[3] * scale + bias[sl * 16 + cq * 4 + 3], 0.f);
    H8u pk16;
    pk16.h[0] = __floats2half2_rn(o0, o1);
    pk16.h[1] = __floats2half2_rn(o2, o3);
    *(uint2*)(As + (size_t)node * 16 + cq * 4) = pk16.u;
}

// ============ classifier: out = A16 @ Wc + bc  (A16 slice-major) ======
__global__ __launch_bounds__(256) void classify16(const __half* __restrict__ A,
                                                  const float* __restrict__ Wc,
                                                  const float* __restrict__ bc,
                                                  float* __restrict__ out, int n) {
    int node = blockIdx.x * 4 + (threadIdx.x >> 6);
    if (node >= n) return;
    int lane = threadIdx.x & 63;
    int col = lane * 2;
    int sl = col >> 4, off = col & 15;
    __half2 h2 = *(const __half2*)(A + (size_t)sl * NSL16 + (size_t)node * 16 + off);
    float2 f = __half22float2(h2);
    float o0 = f.x * Wc[col * 2]       + f.y * Wc[(col + 1) * 2];
    float o1 = f.x * Wc[col * 2 + 1]   + f.y * Wc[(col + 1) * 2 + 1];
#pragma unroll
    for (int offx = 32; offx; offx >>= 1) {
        o0 += __shfl_xor(o0, offx);
        o1 += __shfl_xor(o1, offx);
    }
    if (lane == 0) {
        out[(size_t)node * 2 + 0] = o0 + bc[0];
        out[(size_t)node * 2 + 1] = o1 + bc[1];
    }
}

extern "C" void kernel_launch(void* const* d_in, const int* in_sizes, int n_in,
                              void* d_out, int out_size, void* d_ws, size_t ws_size,
                              hipStream_t stream) {
    const float* x   = (const float*)d_in[0];
    const int*   ei  = (const int*)d_in[1];
    const int*   src = ei;
    const int*   dst = ei + NEDGES;
    const float* Ws[3]  = {(const float*)d_in[2], (const float*)d_in[6], (const float*)d_in[10]};
    const float* ass[3] = {(const float*)d_in[3], (const float*)d_in[7], (const float*)d_in[11]};
    const float* ads[3] = {(const float*)d_in[4], (const float*)d_in[8], (const float*)d_in[12]};
    const float* bs[3]  = {(const float*)d_in[5], (const float*)d_in[9], (const float*)d_in[13]};
    const float* Wc = (const float*)d_in[14];
    const float* bc = (const float*)d_in[15];
    float* out = (float*)d_out;

    const int n = NNODES;

    // ---- workspace (~77 MB) ----
    __half*   h16  = (__half*)d_ws;                     // N*128 fp16 (slice-major)
    __half*   a16  = h16 + (size_t)n * DIM;             // N*128 fp16 (slice-major)
    __half*   wt16 = a16 + (size_t)n * DIM;             // 3*128*128 fp16 (W^T)
    float*    sbuf = (float*)(wt16 + 3 * 128 * 128);    // N
    float*    dbuf = sbuf + n;                          // N
    int*      rowptr4     = (int*)(dbuf + n);           // N
    int*      cnts        = rowptr4 + n;                // N
    int*      csr_src     = cnts + n;                   // CSRSZ
    unsigned* packed2     = (unsigned*)(csr_src + CSRSZ); // CSRSZ
    int*      packed      = (int*)(packed2 + CSRSZ);    // E (build temp)
    int*      blockcounts = packed + NEDGES;            // NB*NCH
    int*      bbase       = blockcounts + NB * NCH;     // NB+1
    int*      btotal      = bbase + NB + 1;             // NB

    const int g64        = (n + 63) / 64;
    const int alpha_grid = (n + 7) / 8;           // 12500
    const int cls_grid   = (n + 3) / 4;           // 25000
    const int agg_grid   = ((n + 63) / 64) * 8;   // 12504

    // ---- one-time prep ----
    wprep<<<192, 256, 0, stream>>>(Ws[0], Ws[1], Ws[2], wt16);
    bucket_count<<<NCH, 512, 0, stream>>>(dst, blockcounts);
    bucket_scan_a<<<NB, NCH, 0, stream>>>(blockcounts, btotal);
    bucket_scan_b<<<1, 1024, 0, stream>>>(btotal, bbase);
    bucket_scatter<<<NCH, 512, 0, stream>>>(src, dst, blockcounts, bbase, packed);
    bucket_csr<<<NB, 256, 0, stream>>>(packed, bbase, rowptr4, cnts, csr_src);

    // ---- 3 GAT layers ----
    for (int layer = 0; layer < 3; ++layer) {
        const __half* wl = wt16 + (size_t)layer * 128 * 128;
        if (layer == 0)
            gemm_mfma<false><<<g64, 256, 0, stream>>>(x, a16, wl, ass[0], ads[0],
                                                      h16, sbuf, dbuf, n);
        else
            gemm_mfma<true><<<g64, 256, 0, stream>>>(x, a16, wl, ass[layer], ads[layer],
                                                     h16, sbuf, dbuf, n);
        gat_alpha<<<alpha_grid, 256, 0, stream>>>(rowptr4, cnts, csr_src, sbuf, dbuf,
                                                  packed2, n);
        gat_agg<<<agg_grid, 256, 0, stream>>>(rowptr4, cnts, packed2, h16, bs[layer], a16, n);
    }
    classify16<<<cls_grid, 256, 0, stream>>>(a16, Wc, bc, out, n);
}